// Round 1
// baseline (262.562 us; speedup 1.0000x reference)
//
#include <hip/hip_runtime.h>
#include <stdint.h>

typedef unsigned short u16;
typedef unsigned int u32;
typedef __bf16 bf16x8 __attribute__((ext_vector_type(8)));
typedef float f32x4 __attribute__((ext_vector_type(4)));

#define N_NODES 10000
#define N_EDGES 160000
#define F_IN    3703
#define HDIM    1024
#define CDIM    6
#define MP      10112   // 79*128
#define KP      3712    // 58*64
#define KT      58

static __device__ __forceinline__ u16 f2bf(float f) {
    u32 u = __builtin_bit_cast(u32, f);
    u32 r = (u + 0x7fffu + ((u >> 16) & 1u)) >> 16;
    return (u16)r;
}
static __device__ __forceinline__ float bf2f(u16 b) {
    return __builtin_bit_cast(float, ((u32)b) << 16);
}

#define GL2LDS(g, l) __builtin_amdgcn_global_load_lds(                         \
    (const __attribute__((address_space(1))) void*)(g),                        \
    (__attribute__((address_space(3))) void*)(l), 16, 0, 0)

// ---------------- CSR build ----------------
__global__ void k_init(int* counts, int* cursor) {
    int i = blockIdx.x * 256 + threadIdx.x;
    if (i < N_NODES) { counts[i] = 0; cursor[i] = 0; }
}

__global__ void k_count(const int* __restrict__ ei, int* counts) {
    int e = blockIdx.x * 256 + threadIdx.x;
    if (e < N_EDGES) {
        int dst = ei[N_EDGES + e];
        atomicAdd(&counts[dst], 1);
    }
}

__global__ void k_scan(const int* __restrict__ counts, int* __restrict__ offsets,
                       float* __restrict__ inv_sqrt) {
    __shared__ int sums[1024];
    int t = threadIdx.x;
    int local[10];
    int s = 0;
    #pragma unroll
    for (int i = 0; i < 10; i++) {
        int idx = t * 10 + i;
        int v = (idx < N_NODES) ? counts[idx] : 0;
        local[i] = s; s += v;
    }
    sums[t] = s;
    __syncthreads();
    for (int off = 1; off < 1024; off <<= 1) {
        int v = (t >= off) ? sums[t - off] : 0;
        __syncthreads();
        sums[t] += v;
        __syncthreads();
    }
    int base = (t == 0) ? 0 : sums[t - 1];
    #pragma unroll
    for (int i = 0; i < 10; i++) {
        int idx = t * 10 + i;
        if (idx < N_NODES) {
            offsets[idx] = base + local[i];
            inv_sqrt[idx] = rsqrtf((float)(counts[idx] + 1));
        }
    }
    if (t == 1023) offsets[N_NODES] = sums[1023];
}

__global__ void k_fill(const int* __restrict__ ei, const int* __restrict__ offsets,
                       int* cursor, int* __restrict__ edge_src) {
    int e = blockIdx.x * 256 + threadIdx.x;
    if (e < N_EDGES) {
        int src = ei[e];
        int dst = ei[N_EDGES + e];
        int pos = atomicAdd(&cursor[dst], 1);
        edge_src[offsets[dst] + pos] = src;
    }
}

// ---------------- conversions ----------------
__global__ void k_cvt_x(const float* __restrict__ x, u16* __restrict__ A) {
    const int KP4 = KP / 4;             // 928
    int i = blockIdx.x * 256 + threadIdx.x;
    if (i >= MP * KP4) return;
    int m = i / KP4;
    int k4 = (i - m * KP4) * 4;
    float v0 = 0.f, v1 = 0.f, v2 = 0.f, v3 = 0.f;
    if (m < N_NODES) {
        const float* xp = x + (size_t)m * F_IN;
        if (k4 + 3 < F_IN) {
            v0 = xp[k4]; v1 = xp[k4 + 1]; v2 = xp[k4 + 2]; v3 = xp[k4 + 3];
        } else {
            if (k4     < F_IN) v0 = xp[k4];
            if (k4 + 1 < F_IN) v1 = xp[k4 + 1];
            if (k4 + 2 < F_IN) v2 = xp[k4 + 2];
            if (k4 + 3 < F_IN) v3 = xp[k4 + 3];
        }
    }
    ushort4 o;
    o.x = f2bf(v0); o.y = f2bf(v1); o.z = f2bf(v2); o.w = f2bf(v3);
    *(ushort4*)&A[(size_t)m * KP + k4] = o;
}

// W1 [F_IN x HDIM] row-major -> BT [HDIM x KP] row-major (bf16), zero-padded K
__global__ void k_cvt_w1t(const float* __restrict__ W1, u16* __restrict__ BT) {
    __shared__ u16 tile[64][66];
    int k0 = blockIdx.x * 64, n0 = blockIdx.y * 64;
    int tx = threadIdx.x & 63, ty = threadIdx.x >> 6;  // 64 x 4
    #pragma unroll
    for (int i = 0; i < 16; i++) {
        int kk = ty + i * 4;
        int k = k0 + kk;
        float v = (k < F_IN) ? W1[(size_t)k * HDIM + n0 + tx] : 0.f;
        tile[kk][tx] = f2bf(v);
    }
    __syncthreads();
    #pragma unroll
    for (int i = 0; i < 16; i++) {
        int nn = ty + i * 4;
        BT[(size_t)(n0 + nn) * KP + k0 + tx] = tile[tx][nn];
    }
}

// ---------------- GEMM1: [MP x KP] x [KP x HDIM] bf16 -> H1 bf16 ----------------
__global__ __launch_bounds__(256) void k_gemm1(const u16* __restrict__ A,
                                               const u16* __restrict__ BT,
                                               u16* __restrict__ H1) {
    __shared__ __align__(16) u16 As[128 * 64];
    __shared__ __align__(16) u16 Bs[128 * 64];
    const int tid = threadIdx.x;
    const int lane = tid & 63;
    const int wid = tid >> 6;
    const int wm = wid >> 1, wn = wid & 1;
    const int bn = blockIdx.x, bm = blockIdx.y;

    // staging per-lane constants (4 issues/wave for A, 4 for B; 16 issues = full tile)
    int srow[4], scol[4], sdst[4];
    #pragma unroll
    for (int j = 0; j < 4; j++) {
        int q = wid * 4 + j;
        int e = q * 512 + lane * 8;     // linear elem offset in LDS tile
        int row = e >> 6, c = e & 63;
        srow[j] = row;
        scol[j] = c ^ ((row & 7) << 3); // inverse-swizzled global source col
        sdst[j] = q * 512;              // wave-uniform LDS base (elems)
    }
    const u16* Abase = A + (size_t)bm * 128 * KP;
    const u16* Bbase = BT + (size_t)bn * 128 * KP;

    f32x4 acc[4][4];
    #pragma unroll
    for (int i = 0; i < 4; i++)
        #pragma unroll
        for (int j = 0; j < 4; j++)
            acc[i][j] = (f32x4)0.f;

    for (int kt = 0; kt < KT; ++kt) {
        const int k0 = kt * 64;
        #pragma unroll
        for (int j = 0; j < 4; j++)
            GL2LDS(Abase + srow[j] * KP + k0 + scol[j], As + sdst[j]);
        #pragma unroll
        for (int j = 0; j < 4; j++)
            GL2LDS(Bbase + srow[j] * KP + k0 + scol[j], Bs + sdst[j]);
        __syncthreads();

        const int rA = wm * 64 + (lane & 15);
        const int rB = wn * 64 + (lane & 15);
        const int cb = (lane >> 4) << 3;
        #pragma unroll
        for (int kk = 0; kk < 2; kk++) {
            bf16x8 av[4], bv[4];
            const int cc = kk * 32 + cb;
            #pragma unroll
            for (int i = 0; i < 4; i++) {
                int r = rA + i * 16;
                av[i] = *(const bf16x8*)(As + r * 64 + (cc ^ ((r & 7) << 3)));
                int r2 = rB + i * 16;
                bv[i] = *(const bf16x8*)(Bs + r2 * 64 + (cc ^ ((r2 & 7) << 3)));
            }
            #pragma unroll
            for (int i = 0; i < 4; i++)
                #pragma unroll
                for (int j = 0; j < 4; j++)
                    acc[i][j] = __builtin_amdgcn_mfma_f32_16x16x32_bf16(
                        av[i], bv[j], acc[i][j], 0, 0, 0);
        }
        __syncthreads();
    }

    // epilogue: C[row][col], row=(lane>>4)*4+r, col=lane&15 within each 16x16 frag
    const int cr = (lane >> 4) * 4;
    const int ccol = lane & 15;
    #pragma unroll
    for (int i = 0; i < 4; i++) {
        #pragma unroll
        for (int j = 0; j < 4; j++) {
            #pragma unroll
            for (int r = 0; r < 4; r++) {
                int row = bm * 128 + wm * 64 + i * 16 + cr + r;
                if (row < N_NODES) {
                    int col = bn * 128 + wn * 64 + j * 16 + ccol;
                    H1[(size_t)row * HDIM + col] = f2bf(acc[i][j][r]);
                }
            }
        }
    }
}

// ---------------- aggregation 1: AGG1 = relu(Ahat*H1 + b1), fp32 ----------------
__global__ void k_agg1(const u16* __restrict__ H1, const int* __restrict__ offsets,
                       const int* __restrict__ edge_src, const float* __restrict__ inv_sqrt,
                       const float* __restrict__ b1, float* __restrict__ AGG1) {
    int node = blockIdx.x;
    int t = threadIdx.x;
    int f = t * 4;
    float is_n = inv_sqrt[node];
    float a0, a1, a2, a3;
    {
        float w = is_n * is_n;  // self-loop
        ushort4 v = *(const ushort4*)(H1 + (size_t)node * HDIM + f);
        a0 = bf2f(v.x) * w; a1 = bf2f(v.y) * w; a2 = bf2f(v.z) * w; a3 = bf2f(v.w) * w;
    }
    int beg = offsets[node], end = offsets[node + 1];
    for (int e = beg; e < end; ++e) {
        int s = edge_src[e];
        float w = inv_sqrt[s] * is_n;
        ushort4 v = *(const ushort4*)(H1 + (size_t)s * HDIM + f);
        a0 += bf2f(v.x) * w; a1 += bf2f(v.y) * w; a2 += bf2f(v.z) * w; a3 += bf2f(v.w) * w;
    }
    float4 o;
    o.x = fmaxf(a0 + b1[f + 0], 0.f);
    o.y = fmaxf(a1 + b1[f + 1], 0.f);
    o.z = fmaxf(a2 + b1[f + 2], 0.f);
    o.w = fmaxf(a3 + b1[f + 3], 0.f);
    *(float4*)&AGG1[(size_t)node * HDIM + f] = o;
}

// ---------------- GEMM2: H2 = AGG1 @ W2 (fp32 vector, wave-per-row) ----------------
__global__ void k_gemm2(const float* __restrict__ AGG1, const float* __restrict__ W2,
                        float* __restrict__ H2) {
    __shared__ float w2l[CDIM * HDIM];  // transposed [c][k], 24 KB
    int t = threadIdx.x;
    for (int i = t; i < HDIM * CDIM; i += 256) {
        int k = i / CDIM, c = i - k * CDIM;
        w2l[c * HDIM + k] = W2[i];
    }
    __syncthreads();
    int lane = t & 63, wv = t >> 6;
    int row = blockIdx.x * 4 + wv;
    if (row >= N_NODES) return;
    const float* xp = AGG1 + (size_t)row * HDIM;
    float acc[6] = {0.f, 0.f, 0.f, 0.f, 0.f, 0.f};
    #pragma unroll
    for (int i = 0; i < 16; i++) {
        int k = lane + i * 64;
        float xv = xp[k];
        #pragma unroll
        for (int c = 0; c < 6; c++) acc[c] += xv * w2l[c * HDIM + k];
    }
    #pragma unroll
    for (int c = 0; c < 6; c++) {
        #pragma unroll
        for (int off = 32; off > 0; off >>= 1) acc[c] += __shfl_xor(acc[c], off);
    }
    if (lane == 0) {
        #pragma unroll
        for (int c = 0; c < 6; c++) H2[(size_t)row * CDIM + c] = acc[c];
    }
}

// ---------------- aggregation 2 + bias + log_softmax -> out ----------------
__global__ void k_agg2(const float* __restrict__ H2, const int* __restrict__ offsets,
                       const int* __restrict__ edge_src, const float* __restrict__ inv_sqrt,
                       const float* __restrict__ b2, float* __restrict__ out) {
    int gt = blockIdx.x * 256 + threadIdx.x;
    int node = gt >> 3, sub = gt & 7;
    if (node >= N_NODES) return;  // whole 8-groups retire together (80000 % 8 == 0)
    float is_n = inv_sqrt[node];
    float acc[6] = {0.f, 0.f, 0.f, 0.f, 0.f, 0.f};
    int beg = offsets[node], end = offsets[node + 1];
    for (int e = beg + sub; e < end; e += 8) {
        int s = edge_src[e];
        float w = inv_sqrt[s] * is_n;
        #pragma unroll
        for (int c = 0; c < 6; c++) acc[c] += H2[(size_t)s * CDIM + c] * w;
    }
    if (sub == 0) {
        float w = is_n * is_n;
        #pragma unroll
        for (int c = 0; c < 6; c++) acc[c] += H2[(size_t)node * CDIM + c] * w;
    }
    #pragma unroll
    for (int off = 1; off < 8; off <<= 1) {
        #pragma unroll
        for (int c = 0; c < 6; c++) acc[c] += __shfl_xor(acc[c], off);
    }
    if (sub == 0) {
        float z[6];
        #pragma unroll
        for (int c = 0; c < 6; c++) z[c] = acc[c] + b2[c];
        float m = z[0];
        #pragma unroll
        for (int c = 1; c < 6; c++) m = fmaxf(m, z[c]);
        float ssum = 0.f;
        #pragma unroll
        for (int c = 0; c < 6; c++) ssum += __expf(z[c] - m);
        float l = m + logf(ssum);
        #pragma unroll
        for (int c = 0; c < 6; c++) out[(size_t)node * CDIM + c] = z[c] - l;
    }
}

// ---------------- launch ----------------
extern "C" void kernel_launch(void* const* d_in, const int* in_sizes, int n_in,
                              void* d_out, int out_size, void* d_ws, size_t ws_size,
                              hipStream_t stream) {
    const float* x  = (const float*)d_in[0];
    const int*   ei = (const int*)d_in[1];     // harness passes integers as int32
    const float* W1 = (const float*)d_in[2];
    const float* b1 = (const float*)d_in[3];
    const float* W2 = (const float*)d_in[4];
    const float* b2 = (const float*)d_in[5];
    float* out = (float*)d_out;

    char* ws = (char*)d_ws;
    size_t off = 0;
    auto alloc = [&](size_t bytes) -> void* {
        void* p = ws + off;
        off += (bytes + 255) & ~(size_t)255;
        return p;
    };
    u16* A        = (u16*)alloc((size_t)MP * KP * 2);       // 75.1 MB ; later reused as AGG1
    u16* BT       = (u16*)alloc((size_t)HDIM * KP * 2);     // 7.6 MB  ; later reused as H2
    u16* H1       = (u16*)alloc((size_t)N_NODES * HDIM * 2);// 20.5 MB
    int* counts   = (int*)alloc(N_NODES * 4);
    int* cursor   = (int*)alloc(N_NODES * 4);
    int* offsets  = (int*)alloc((N_NODES + 1) * 4);
    float* inv_sq = (float*)alloc(N_NODES * 4);
    int* edge_src = (int*)alloc(N_EDGES * 4);
    float* AGG1 = (float*)A;   // alias: A dead after k_gemm1
    float* H2   = (float*)BT;  // alias: BT dead after k_gemm1

    k_init<<<(N_NODES + 255) / 256, 256, 0, stream>>>(counts, cursor);
    k_count<<<(N_EDGES + 255) / 256, 256, 0, stream>>>(ei, counts);
    k_scan<<<1, 1024, 0, stream>>>(counts, offsets, inv_sq);
    k_fill<<<(N_EDGES + 255) / 256, 256, 0, stream>>>(ei, offsets, cursor, edge_src);

    k_cvt_x<<<(MP * (KP / 4) + 255) / 256, 256, 0, stream>>>(x, A);
    dim3 gT(KP / 64, HDIM / 64);
    k_cvt_w1t<<<gT, 256, 0, stream>>>(W1, BT);

    dim3 gG(HDIM / 128, MP / 128);  // (8, 79)
    k_gemm1<<<gG, 256, 0, stream>>>(A, BT, H1);

    k_agg1<<<N_NODES, 256, 0, stream>>>(H1, offsets, edge_src, inv_sq, b1, AGG1);
    k_gemm2<<<N_NODES / 4, 256, 0, stream>>>(AGG1, W2, H2);
    k_agg2<<<(N_NODES * 8 + 255) / 256, 256, 0, stream>>>(H2, offsets, edge_src, inv_sq, b2, out);
}

// Round 2
// 240.067 us; speedup vs baseline: 1.0937x; 1.0937x over previous
//
#include <hip/hip_runtime.h>
#include <stdint.h>

typedef unsigned short u16;
typedef unsigned int u32;
typedef __bf16 bf16x8 __attribute__((ext_vector_type(8)));
typedef float f32x4 __attribute__((ext_vector_type(4)));

#define N_NODES 10000
#define N_EDGES 160000
#define F_IN    3703
#define HDIM    1024
#define CDIM    6
#define MP      10112   // 79*128
#define KP      3712    // 58*64
#define KT      58

static __device__ __forceinline__ u16 f2bf(float f) {
    u32 u = __builtin_bit_cast(u32, f);
    u32 r = (u + 0x7fffu + ((u >> 16) & 1u)) >> 16;
    return (u16)r;
}
static __device__ __forceinline__ float bf2f(u16 b) {
    return __builtin_bit_cast(float, ((u32)b) << 16);
}

#define GL2LDS(g, l) __builtin_amdgcn_global_load_lds(                         \
    (const __attribute__((address_space(1))) void*)(g),                        \
    (__attribute__((address_space(3))) void*)(l), 16, 0, 0)

// ---------------- CSR build ----------------
__global__ void k_count(const int* __restrict__ ei, int* counts) {
    int e = blockIdx.x * 256 + threadIdx.x;
    if (e < N_EDGES) {
        int dst = ei[N_EDGES + e];
        atomicAdd(&counts[dst], 1);
    }
}

__global__ void k_scan(const int* __restrict__ counts, int* __restrict__ offsets,
                       float* __restrict__ inv_sqrt) {
    __shared__ int sums[1024];
    int t = threadIdx.x;
    int local[10];
    int s = 0;
    #pragma unroll
    for (int i = 0; i < 10; i++) {
        int idx = t * 10 + i;
        int v = (idx < N_NODES) ? counts[idx] : 0;
        local[i] = s; s += v;
    }
    sums[t] = s;
    __syncthreads();
    for (int off = 1; off < 1024; off <<= 1) {
        int v = (t >= off) ? sums[t - off] : 0;
        __syncthreads();
        sums[t] += v;
        __syncthreads();
    }
    int base = (t == 0) ? 0 : sums[t - 1];
    #pragma unroll
    for (int i = 0; i < 10; i++) {
        int idx = t * 10 + i;
        if (idx < N_NODES) {
            offsets[idx] = base + local[i];
            inv_sqrt[idx] = rsqrtf((float)(counts[idx] + 1));
        }
    }
    if (t == 1023) offsets[N_NODES] = sums[1023];
}

__global__ void k_fill(const int* __restrict__ ei, const int* __restrict__ offsets,
                       int* cursor, int* __restrict__ edge_src) {
    int e = blockIdx.x * 256 + threadIdx.x;
    if (e < N_EDGES) {
        int src = ei[e];
        int dst = ei[N_EDGES + e];
        int pos = atomicAdd(&cursor[dst], 1);
        edge_src[offsets[dst] + pos] = src;
    }
}

// ---------------- conversions ----------------
__global__ void k_cvt_x(const float* __restrict__ x, u16* __restrict__ A) {
    const int KP4 = KP / 4;             // 928
    int i = blockIdx.x * 256 + threadIdx.x;
    if (i >= MP * KP4) return;
    int m = i / KP4;
    int k4 = (i - m * KP4) * 4;
    float v0 = 0.f, v1 = 0.f, v2 = 0.f, v3 = 0.f;
    if (m < N_NODES) {
        const float* xp = x + (size_t)m * F_IN;
        if (k4 + 3 < F_IN) {
            v0 = xp[k4]; v1 = xp[k4 + 1]; v2 = xp[k4 + 2]; v3 = xp[k4 + 3];
        } else {
            if (k4     < F_IN) v0 = xp[k4];
            if (k4 + 1 < F_IN) v1 = xp[k4 + 1];
            if (k4 + 2 < F_IN) v2 = xp[k4 + 2];
            if (k4 + 3 < F_IN) v3 = xp[k4 + 3];
        }
    }
    ushort4 o;
    o.x = f2bf(v0); o.y = f2bf(v1); o.z = f2bf(v2); o.w = f2bf(v3);
    *(ushort4*)&A[(size_t)m * KP + k4] = o;
}

// W1 [F_IN x HDIM] row-major -> BT [HDIM x KP] row-major (bf16), zero-padded K
__global__ void k_cvt_w1t(const float* __restrict__ W1, u16* __restrict__ BT) {
    __shared__ u16 tile[64][66];
    int k0 = blockIdx.x * 64, n0 = blockIdx.y * 64;
    int tx = threadIdx.x & 63, ty = threadIdx.x >> 6;  // 64 x 4
    #pragma unroll
    for (int i = 0; i < 16; i++) {
        int kk = ty + i * 4;
        int k = k0 + kk;
        float v = (k < F_IN) ? W1[(size_t)k * HDIM + n0 + tx] : 0.f;
        tile[kk][tx] = f2bf(v);
    }
    __syncthreads();
    #pragma unroll
    for (int i = 0; i < 16; i++) {
        int nn = ty + i * 4;
        BT[(size_t)(n0 + nn) * KP + k0 + tx] = tile[tx][nn];
    }
}

// ---------------- GEMM1: [MP x KP] x [KP x HDIM] bf16 -> H1 bf16 ----------------
__global__ __launch_bounds__(256) void k_gemm1(const u16* __restrict__ A,
                                               const u16* __restrict__ BT,
                                               u16* __restrict__ H1) {
    __shared__ __align__(16) u16 As[128 * 64];
    __shared__ __align__(16) u16 Bs[128 * 64];
    const int tid = threadIdx.x;
    const int lane = tid & 63;
    const int wid = tid >> 6;
    const int wm = wid >> 1, wn = wid & 1;

    // XCD-aware bijective swizzle: orig%8 = XCD; give each XCD a contiguous
    // bm-major chunk so each A panel is fetched by exactly ONE XCD's L2.
    const u32 orig = (u32)blockIdx.y * 8u + (u32)blockIdx.x;   // 0..631
    const u32 lin  = (orig & 7u) * 79u + (orig >> 3);          // bijective (632=8*79)
    const int bm = (int)(lin >> 3);
    const int bn = (int)(lin & 7u);

    // staging per-lane constants (4 issues/wave for A, 4 for B; 16 issues = full tile)
    int srow[4], scol[4], sdst[4];
    #pragma unroll
    for (int j = 0; j < 4; j++) {
        int q = wid * 4 + j;
        int e = q * 512 + lane * 8;     // linear elem offset in LDS tile
        int row = e >> 6, c = e & 63;
        srow[j] = row;
        scol[j] = c ^ ((row & 7) << 3); // inverse-swizzled global source col
        sdst[j] = q * 512;              // wave-uniform LDS base (elems)
    }
    const u16* Abase = A + (size_t)bm * 128 * KP;
    const u16* Bbase = BT + (size_t)bn * 128 * KP;

    f32x4 acc[4][4];
    #pragma unroll
    for (int i = 0; i < 4; i++)
        #pragma unroll
        for (int j = 0; j < 4; j++)
            acc[i][j] = (f32x4)0.f;

    for (int kt = 0; kt < KT; ++kt) {
        const int k0 = kt * 64;
        #pragma unroll
        for (int j = 0; j < 4; j++)
            GL2LDS(Abase + srow[j] * KP + k0 + scol[j], As + sdst[j]);
        #pragma unroll
        for (int j = 0; j < 4; j++)
            GL2LDS(Bbase + srow[j] * KP + k0 + scol[j], Bs + sdst[j]);
        __syncthreads();

        const int rA = wm * 64 + (lane & 15);
        const int rB = wn * 64 + (lane & 15);
        const int cb = (lane >> 4) << 3;
        #pragma unroll
        for (int kk = 0; kk < 2; kk++) {
            bf16x8 av[4], bv[4];
            const int cc = kk * 32 + cb;
            #pragma unroll
            for (int i = 0; i < 4; i++) {
                int r = rA + i * 16;
                av[i] = *(const bf16x8*)(As + r * 64 + (cc ^ ((r & 7) << 3)));
                int r2 = rB + i * 16;
                bv[i] = *(const bf16x8*)(Bs + r2 * 64 + (cc ^ ((r2 & 7) << 3)));
            }
            #pragma unroll
            for (int i = 0; i < 4; i++)
                #pragma unroll
                for (int j = 0; j < 4; j++)
                    acc[i][j] = __builtin_amdgcn_mfma_f32_16x16x32_bf16(
                        av[i], bv[j], acc[i][j], 0, 0, 0);
        }
        __syncthreads();
    }

    // epilogue: C[row][col], row=(lane>>4)*4+r, col=lane&15 within each 16x16 frag
    const int cr = (lane >> 4) * 4;
    const int ccol = lane & 15;
    #pragma unroll
    for (int i = 0; i < 4; i++) {
        #pragma unroll
        for (int j = 0; j < 4; j++) {
            #pragma unroll
            for (int r = 0; r < 4; r++) {
                int row = bm * 128 + wm * 64 + i * 16 + cr + r;
                if (row < N_NODES) {
                    int col = bn * 128 + wn * 64 + j * 16 + ccol;
                    H1[(size_t)row * HDIM + col] = f2bf(acc[i][j][r]);
                }
            }
        }
    }
}

// ------- fused: AGG1 = relu(Ahat*H1 + b1) (in regs), H2 = AGG1 @ W2 -------
__global__ void k_agg1g2(const u16* __restrict__ H1, const int* __restrict__ offsets,
                         const int* __restrict__ edge_src, const float* __restrict__ inv_sqrt,
                         const float* __restrict__ b1, const float* __restrict__ W2,
                         float* __restrict__ H2) {
    __shared__ float red[4][8];
    int node = blockIdx.x;
    int t = threadIdx.x;
    int f = t * 4;
    float is_n = inv_sqrt[node];
    float a0, a1, a2, a3;
    {
        float w = is_n * is_n;  // self-loop
        ushort4 v = *(const ushort4*)(H1 + (size_t)node * HDIM + f);
        a0 = bf2f(v.x) * w; a1 = bf2f(v.y) * w; a2 = bf2f(v.z) * w; a3 = bf2f(v.w) * w;
    }
    int beg = offsets[node], end = offsets[node + 1];
    for (int e = beg; e < end; ++e) {
        int s = edge_src[e];
        float w = inv_sqrt[s] * is_n;
        ushort4 v = *(const ushort4*)(H1 + (size_t)s * HDIM + f);
        a0 += bf2f(v.x) * w; a1 += bf2f(v.y) * w; a2 += bf2f(v.z) * w; a3 += bf2f(v.w) * w;
    }
    float4 bb = *(const float4*)(b1 + f);
    float z0 = fmaxf(a0 + bb.x, 0.f);
    float z1 = fmaxf(a1 + bb.y, 0.f);
    float z2 = fmaxf(a2 + bb.z, 0.f);
    float z3 = fmaxf(a3 + bb.w, 0.f);
    float acc[6];
    #pragma unroll
    for (int c = 0; c < 6; c++)
        acc[c] = z0 * W2[(size_t)f * 6 + c] + z1 * W2[(size_t)(f + 1) * 6 + c]
               + z2 * W2[(size_t)(f + 2) * 6 + c] + z3 * W2[(size_t)(f + 3) * 6 + c];
    #pragma unroll
    for (int c = 0; c < 6; c++) {
        #pragma unroll
        for (int off = 32; off > 0; off >>= 1) acc[c] += __shfl_xor(acc[c], off);
    }
    int lane = t & 63, wv = t >> 6;
    if (lane == 0) {
        #pragma unroll
        for (int c = 0; c < 6; c++) red[wv][c] = acc[c];
    }
    __syncthreads();
    if (t < 6) {
        float s = red[0][t] + red[1][t] + red[2][t] + red[3][t];
        H2[(size_t)node * CDIM + t] = s;
    }
}

// ---------------- aggregation 2 + bias + log_softmax -> out ----------------
__global__ void k_agg2(const float* __restrict__ H2, const int* __restrict__ offsets,
                       const int* __restrict__ edge_src, const float* __restrict__ inv_sqrt,
                       const float* __restrict__ b2, float* __restrict__ out) {
    int gt = blockIdx.x * 256 + threadIdx.x;
    int node = gt >> 3, sub = gt & 7;
    if (node >= N_NODES) return;  // whole 8-groups retire together (80000 % 8 == 0)
    float is_n = inv_sqrt[node];
    float acc[6] = {0.f, 0.f, 0.f, 0.f, 0.f, 0.f};
    int beg = offsets[node], end = offsets[node + 1];
    for (int e = beg + sub; e < end; e += 8) {
        int s = edge_src[e];
        float w = inv_sqrt[s] * is_n;
        #pragma unroll
        for (int c = 0; c < 6; c++) acc[c] += H2[(size_t)s * CDIM + c] * w;
    }
    if (sub == 0) {
        float w = is_n * is_n;
        #pragma unroll
        for (int c = 0; c < 6; c++) acc[c] += H2[(size_t)node * CDIM + c] * w;
    }
    #pragma unroll
    for (int off = 1; off < 8; off <<= 1) {
        #pragma unroll
        for (int c = 0; c < 6; c++) acc[c] += __shfl_xor(acc[c], off);
    }
    if (sub == 0) {
        float z[6];
        #pragma unroll
        for (int c = 0; c < 6; c++) z[c] = acc[c] + b2[c];
        float m = z[0];
        #pragma unroll
        for (int c = 1; c < 6; c++) m = fmaxf(m, z[c]);
        float ssum = 0.f;
        #pragma unroll
        for (int c = 0; c < 6; c++) ssum += __expf(z[c] - m);
        float l = m + logf(ssum);
        #pragma unroll
        for (int c = 0; c < 6; c++) out[(size_t)node * CDIM + c] = z[c] - l;
    }
}

// ---------------- launch ----------------
extern "C" void kernel_launch(void* const* d_in, const int* in_sizes, int n_in,
                              void* d_out, int out_size, void* d_ws, size_t ws_size,
                              hipStream_t stream) {
    const float* x  = (const float*)d_in[0];
    const int*   ei = (const int*)d_in[1];
    const float* W1 = (const float*)d_in[2];
    const float* b1 = (const float*)d_in[3];
    const float* W2 = (const float*)d_in[4];
    const float* b2 = (const float*)d_in[5];
    float* out = (float*)d_out;

    char* ws = (char*)d_ws;
    size_t off = 0;
    auto alloc = [&](size_t bytes) -> void* {
        void* p = ws + off;
        off += (bytes + 255) & ~(size_t)255;
        return p;
    };
    u16* A        = (u16*)alloc((size_t)MP * KP * 2);       // 75.1 MB
    u16* BT       = (u16*)alloc((size_t)HDIM * KP * 2);     // 7.6 MB ; reused as H2
    u16* H1       = (u16*)alloc((size_t)N_NODES * HDIM * 2);// 20.5 MB
    int* counts   = (int*)alloc(N_NODES * 4);
    int* cursor   = (int*)alloc(N_NODES * 4);
    int* offsets  = (int*)alloc((N_NODES + 1) * 4);
    float* inv_sq = (float*)alloc(N_NODES * 4);
    int* edge_src = (int*)alloc(N_EDGES * 4);
    float* H2 = (float*)BT;  // alias: BT dead after k_gemm1

    hipMemsetAsync(counts, 0, N_NODES * 4, stream);
    hipMemsetAsync(cursor, 0, N_NODES * 4, stream);
    k_count<<<(N_EDGES + 255) / 256, 256, 0, stream>>>(ei, counts);
    k_scan<<<1, 1024, 0, stream>>>(counts, offsets, inv_sq);
    k_fill<<<(N_EDGES + 255) / 256, 256, 0, stream>>>(ei, offsets, cursor, edge_src);

    k_cvt_x<<<(MP * (KP / 4) + 255) / 256, 256, 0, stream>>>(x, A);
    dim3 gT(KP / 64, HDIM / 64);
    k_cvt_w1t<<<gT, 256, 0, stream>>>(W1, BT);

    dim3 gG(HDIM / 128, MP / 128);  // (8, 79)
    k_gemm1<<<gG, 256, 0, stream>>>(A, BT, H1);

    k_agg1g2<<<N_NODES, 256, 0, stream>>>(H1, offsets, edge_src, inv_sq, b1, W2, H2);
    k_agg2<<<(N_NODES * 8 + 255) / 256, 256, 0, stream>>>(H2, offsets, edge_src, inv_sq, b2, out);
}